// Round 1
// baseline (271.082 us; speedup 1.0000x reference)
//
#include <hip/hip_runtime.h>
#include <stdint.h>

// Problem constants
#define DIM    1024
#define RANK   16
#define M_TOT  8192          // 2*4096 rows of x
#define N_TOT  3072          // 3*DIM output features
#define K_TOT  1024

// GEMM tiling: block = 128x128, BK=64, 4 waves, wave tile 64x64 (acc 4x4)
#define BM 128
#define BN 128
#define BK 64

typedef __attribute__((ext_vector_type(8))) short  s8v;   // 8 x bf16 (raw bits)
typedef __attribute__((ext_vector_type(4))) float  f4v;   // MFMA acc

__device__ __forceinline__ unsigned short f2bf(float f) {
    union { float f; unsigned int u; } v; v.f = f;
    unsigned int u = v.u;
    u += 0x7FFFu + ((u >> 16) & 1u);   // round-to-nearest-even
    return (unsigned short)(u >> 16);
}

// Async global->LDS DMA, 16 B/lane. LDS dest is wave-uniform base + lane*16;
// global src is per-lane. (m97 transport: the compiler never auto-emits this.)
__device__ __forceinline__ void gload_lds16(const unsigned short* g,
                                            unsigned short* l) {
    __builtin_amdgcn_global_load_lds(
        (const __attribute__((address_space(1))) void*)g,
        (__attribute__((address_space(3))) void*)l,
        16, 0, 0);
}

// ---------------- Kernel 1: fused prep ----------------
// blocks [0, 8192):     x fp32 -> bf16 (float4 -> ushort4)
// blocks [8192, 11264): fold LoRA into W, fp32 -> bf16
__global__ void prep(const float4* __restrict__ x, ushort4* __restrict__ xb,
                     const float* __restrict__ W,
                     const float* __restrict__ Aq, const float* __restrict__ Bq,
                     const float* __restrict__ Ak, const float* __restrict__ Bk,
                     const float* __restrict__ Av, const float* __restrict__ Bv,
                     const float* __restrict__ alpha_p,
                     unsigned short* __restrict__ Wb) {
    const int tid = threadIdx.x;
    if (blockIdx.x < 8192) {
        int i = blockIdx.x * 256 + tid;      // n4 = 2097152 = 8192*256 exactly
        float4 v = x[i];
        ushort4 o;
        o.x = f2bf(v.x); o.y = f2bf(v.y); o.z = f2bf(v.z); o.w = f2bf(v.w);
        xb[i] = o;
    } else {
        const int o    = blockIdx.x - 8192;  // 0..3071
        const int sel  = o >> 10;            // 0=q 1=k 2=v
        const int orow = o & 1023;
        const float* Am = (sel == 0) ? Aq : (sel == 1) ? Ak : Av;  // [RANK, DIM]
        const float* Bm = (sel == 0) ? Bq : (sel == 1) ? Bk : Bv;  // [DIM, RANK]

        __shared__ float sb[RANK];
        if (tid < RANK) sb[tid] = alpha_p[0] * Bm[orow * RANK + tid];
        __syncthreads();

        for (int d = tid; d < DIM; d += 256) {
            float acc = W[o * DIM + d];
            #pragma unroll
            for (int r = 0; r < RANK; ++r)
                acc += sb[r] * Am[r * DIM + d];
            Wb[o * DIM + d] = f2bf(acc);
        }
    }
}

// ---------------- Kernel 2: bf16 MFMA GEMM, C = Xb * Wb^T + bias ----------------
// m97 transport: global_load_lds_dwordx4 DMA straight into LDS (no VGPR round
// trip, no ds_write). LDS layout is fragment-ordered 1KB chunks (chunk c:
// lane l owns halves [c*512 + l*8, +8)) -- which is exactly the linear
// wave-uniform-base + lane*16 order the DMA writes, so the per-lane GLOBAL
// addresses carry the fragment swizzle (m173 pattern). Schedule is the
// verified 2-barrier m97 loop:
//   barrier -> issue 8 global_load_lds -> barrier (vmcnt(0) drain) -> 32 MFMA.
// Overlap across the ~4 resident blocks/CU hides the drain (m114).
__global__ __launch_bounds__(256, 4)
void gemm_bt(const unsigned short* __restrict__ Xb,
             const unsigned short* __restrict__ Wb,
             const float* __restrict__ bias,
             float* __restrict__ out) {
    __shared__ __align__(16) unsigned short As[BM * BK];  // 16 KB, 16 chunks
    __shared__ __align__(16) unsigned short Bs[BN * BK];  // 16 KB, 16 chunks

    const int tid  = threadIdx.x;
    const int wave = tid >> 6;       // 0..3
    const int lane = tid & 63;
    const int l15  = lane & 15;
    const int lq   = lane >> 4;      // 0..3
    const int wr   = wave >> 1;      // wave row quadrant (0..1)
    const int wc   = wave & 1;       // wave col quadrant (0..1)

    const int bm = blockIdx.x;       // 0..63   (M tiles)
    const int bn = blockIdx.y;       // 0..23   (N tiles)

    // Wave stages A chunks wave*4..+3 and B chunks wave*4..+3.
    // Chunk c: rows (c>>1)*16 + l15, k-cols (c&1)*32 + lq*8 (8 halves / lane).
    const unsigned short* aptr[4];
    const unsigned short* bptr[4];
    unsigned short* alds[4];         // wave-uniform chunk bases
    unsigned short* blds[4];
    #pragma unroll
    for (int u = 0; u < 4; ++u) {
        const int c   = wave * 4 + u;
        const int row = ((c >> 1) << 4) + l15;       // 0..127
        const int col = ((c & 1) << 5) + (lq << 3);  // 0..56
        aptr[u] = Xb + (size_t)(bm * BM + row) * K_TOT + col;
        bptr[u] = Wb + (size_t)(bn * BN + row) * K_TOT + col;
        alds[u] = &As[c * 512];      // DMA writes base + lane*16B = chunk order
        blds[u] = &Bs[c * 512];
    }

    f4v acc[4][4] = {};

    for (int kk = 0; kk < K_TOT; kk += BK) {
        __syncthreads();   // all waves done reading LDS from prev iter
        #pragma unroll
        for (int u = 0; u < 4; ++u) {
            gload_lds16(aptr[u] + kk, alds[u]);
            gload_lds16(bptr[u] + kk, blds[u]);
        }
        __syncthreads();   // compiler-inserted vmcnt(0) drain: tile published

        const s8v* Avp = (const s8v*)As;
        const s8v* Bvp = (const s8v*)Bs;
        #pragma unroll
        for (int t = 0; t < 2; ++t) {          // two k-steps of 32 within BK=64
            s8v af[4], bf[4];
            #pragma unroll
            for (int i = 0; i < 4; ++i) {
                const int ia = wr * 4 + i;     // A row-tile index 0..7
                const int jb = wc * 4 + i;     // B row-tile index 0..7
                af[i] = Avp[(ia * 2 + t) * 64 + lane];
                bf[i] = Bvp[(jb * 2 + t) * 64 + lane];
            }
            #pragma unroll
            for (int i = 0; i < 4; ++i)
                #pragma unroll
                for (int j = 0; j < 4; ++j)
                    acc[i][j] = __builtin_amdgcn_mfma_f32_16x16x32_bf16(
                        af[i], bf[j], acc[i][j], 0, 0, 0);
        }
    }

    // Epilogue: C/D layout col = lane&15, row = (lane>>4)*4 + reg  [m89]
    const int col_base = bn * BN + wc * 64;
    const int row_base = bm * BM + wr * 64 + lq * 4;
    #pragma unroll
    for (int j = 0; j < 4; ++j) {
        const int col = col_base + j * 16 + l15;
        const float bv = bias[col];
        #pragma unroll
        for (int i = 0; i < 4; ++i) {
            const int row = row_base + i * 16;
            #pragma unroll
            for (int r = 0; r < 4; ++r)
                out[(size_t)(row + r) * N_TOT + col] = acc[i][j][r] + bv;
        }
    }
}

extern "C" void kernel_launch(void* const* d_in, const int* in_sizes, int n_in,
                              void* d_out, int out_size, void* d_ws, size_t ws_size,
                              hipStream_t stream) {
    const float* x     = (const float*)d_in[0];   // [2,4096,1024]
    const float* W     = (const float*)d_in[1];   // [3072,1024]
    const float* b     = (const float*)d_in[2];   // [3072]
    const float* Aq    = (const float*)d_in[3];
    const float* Bq    = (const float*)d_in[4];
    const float* Ak    = (const float*)d_in[5];
    const float* Bk    = (const float*)d_in[6];
    const float* Av    = (const float*)d_in[7];
    const float* Bv    = (const float*)d_in[8];
    const float* alpha = (const float*)d_in[9];
    float* out = (float*)d_out;

    unsigned short* xb = (unsigned short*)d_ws;                                      // 16 MB
    unsigned short* Wb = (unsigned short*)((char*)d_ws + (size_t)M_TOT * K_TOT * 2); // +6 MB

    prep<<<8192 + N_TOT, 256, 0, stream>>>((const float4*)x, (ushort4*)xb,
                                           W, Aq, Bq, Ak, Bk, Av, Bv, alpha, Wb);

    dim3 grid(M_TOT / BM, N_TOT / BN);    // 64 x 24 = 1536 blocks
    gemm_bt<<<grid, 256, 0, stream>>>(xb, Wb, b, out);
}

// Round 2
// 260.989 us; speedup vs baseline: 1.0387x; 1.0387x over previous
//
#include <hip/hip_runtime.h>
#include <stdint.h>

// Problem constants
#define DIM    1024
#define RANK   16
#define M_TOT  8192          // 2*4096 rows of x
#define N_TOT  3072          // 3*DIM output features
#define K_TOT  1024

// GEMM tiling: block = 256x128, BK=64, 8 waves (4M x 2N), wave tile 64x64
#define BM 256
#define BN 128
#define BK 64
#define NT (K_TOT / BK)      // 16 K-tiles

typedef __attribute__((ext_vector_type(8))) short  s8v;   // 8 x bf16 (raw bits)
typedef __attribute__((ext_vector_type(4))) float  f4v;   // MFMA acc

__device__ __forceinline__ unsigned short f2bf(float f) {
    union { float f; unsigned int u; } v; v.f = f;
    unsigned int u = v.u;
    u += 0x7FFFu + ((u >> 16) & 1u);   // round-to-nearest-even
    return (unsigned short)(u >> 16);
}

// Async global->LDS DMA, 16 B/lane. LDS dest is wave-uniform base + lane*16;
// global src carries the fragment swizzle (m173 pattern).
__device__ __forceinline__ void gload_lds16(const unsigned short* g,
                                            unsigned short* l) {
    __builtin_amdgcn_global_load_lds(
        (const __attribute__((address_space(1))) void*)g,
        (__attribute__((address_space(3))) void*)l,
        16, 0, 0);
}

// ---------------- Kernel 1: fused prep (unchanged) ----------------
__global__ void prep(const float4* __restrict__ x, ushort4* __restrict__ xb,
                     const float* __restrict__ W,
                     const float* __restrict__ Aq, const float* __restrict__ Bq,
                     const float* __restrict__ Ak, const float* __restrict__ Bk,
                     const float* __restrict__ Av, const float* __restrict__ Bv,
                     const float* __restrict__ alpha_p,
                     unsigned short* __restrict__ Wb) {
    const int tid = threadIdx.x;
    if (blockIdx.x < 8192) {
        int i = blockIdx.x * 256 + tid;      // n4 = 2097152 = 8192*256 exactly
        float4 v = x[i];
        ushort4 o;
        o.x = f2bf(v.x); o.y = f2bf(v.y); o.z = f2bf(v.z); o.w = f2bf(v.w);
        xb[i] = o;
    } else {
        const int o    = blockIdx.x - 8192;  // 0..3071
        const int sel  = o >> 10;            // 0=q 1=k 2=v
        const int orow = o & 1023;
        const float* Am = (sel == 0) ? Aq : (sel == 1) ? Ak : Av;  // [RANK, DIM]
        const float* Bm = (sel == 0) ? Bq : (sel == 1) ? Bk : Bv;  // [DIM, RANK]

        __shared__ float sb[RANK];
        if (tid < RANK) sb[tid] = alpha_p[0] * Bm[orow * RANK + tid];
        __syncthreads();

        for (int d = tid; d < DIM; d += 256) {
            float acc = W[o * DIM + d];
            #pragma unroll
            for (int r = 0; r < RANK; ++r)
                acc += sb[r] * Am[r * DIM + d];
            Wb[o * DIM + d] = f2bf(acc);
        }
    }
}

// ---------------- Kernel 2: bf16 MFMA GEMM, C = Xb * Wb^T + bias ----------------
// Depth-2 counted-vmcnt DMA pipeline (T3/T4-lite):
//   prologue: DMA tile0 -> buf0, tile1 -> buf1              (12 loads/wave)
//   iter kt:  vmcnt(6)  [tile kt landed; kt+1 stays in flight]
//             s_barrier  (all waves' tile-kt chunks visible)
//             compute buf[kt&1]  (ds_read_b128 frags + 32 MFMA x 2 t-steps)
//             s_barrier  (all waves done reading buf[kt&1])
//             DMA tile kt+2 -> buf[kt&1]                    (6 loads/wave)
// Raw s_barrier + inline-asm waits: __syncthreads() would emit the vmcnt(0)
// drain that serialized rounds 0/1. sched_barrier(0) fences pin ordering.
// LDS: fragment-ordered 1KB chunks (chunk c: lane l owns halves
// [c*512 + l*8, +8)) = exactly the linear order global_load_lds writes.
__global__ __launch_bounds__(512, 2)
void gemm_bt(const unsigned short* __restrict__ Xb,
             const unsigned short* __restrict__ Wb,
             const float* __restrict__ bias,
             float* __restrict__ out) {
    __shared__ __align__(16) unsigned short As[2][BM * BK];  // 2 x 32 KB
    __shared__ __align__(16) unsigned short Bs[2][BN * BK];  // 2 x 16 KB

    const int tid  = threadIdx.x;
    const int wave = tid >> 6;       // 0..7
    const int lane = tid & 63;
    const int l15  = lane & 15;
    const int lq   = lane >> 4;      // 0..3
    const int wr   = wave >> 1;      // M quadrant 0..3 (64 rows each)
    const int wc   = wave & 1;       // N half     0..1 (64 cols each)

    // Bijective XCD swizzle: nwg=768, 768%8==0 -> chunk of 96 per XCD.
    // Within an XCD the 32 concurrent blocks share one bn panel (256 KB Wb
    // slab -> L2-resident).
    const int bid  = blockIdx.x;
    const int wgid = (bid & 7) * 96 + (bid >> 3);
    const int bn   = wgid >> 5;      // 0..23
    const int bm   = wgid & 31;      // 0..31

    // Staging assignment: wave w owns A chunks [w*4, w*4+4), B chunks [w*2, +2).
    // Chunk c of a tile: rows (c>>1)*16 + l15, k-cols (c&1)*32 + lq*8.
    const unsigned short* aptr[4];
    const unsigned short* bptr[2];
    int aoff[4], boff[2];            // chunk base offsets (halves) within a buffer
    #pragma unroll
    for (int u = 0; u < 4; ++u) {
        const int c   = wave * 4 + u;                // 0..31
        const int row = ((c >> 1) << 4) + l15;       // 0..255
        const int col = ((c & 1) << 5) + (lq << 3);  // 0..56
        aptr[u] = Xb + (size_t)(bm * BM + row) * K_TOT + col;
        aoff[u] = c * 512;
    }
    #pragma unroll
    for (int u = 0; u < 2; ++u) {
        const int c   = wave * 2 + u;                // 0..15
        const int row = ((c >> 1) << 4) + l15;       // 0..127
        const int col = ((c & 1) << 5) + (lq << 3);
        bptr[u] = Wb + (size_t)(bn * BN + row) * K_TOT + col;
        boff[u] = c * 512;
    }

    // Prologue: tiles 0 and 1 in flight (12 loads/wave, issue order = count order)
    #pragma unroll
    for (int t = 0; t < 2; ++t) {
        #pragma unroll
        for (int u = 0; u < 4; ++u) gload_lds16(aptr[u] + t * BK, &As[t][aoff[u]]);
        #pragma unroll
        for (int u = 0; u < 2; ++u) gload_lds16(bptr[u] + t * BK, &Bs[t][boff[u]]);
    }

    f4v acc[4][4] = {};

    #pragma unroll
    for (int kt = 0; kt < NT; ++kt) {
        const int cur = kt & 1;
        // tile kt resident after this wait; tile kt+1's 6 loads stay in flight
        if (kt < NT - 1) asm volatile("s_waitcnt vmcnt(6)" ::: "memory");
        else             asm volatile("s_waitcnt vmcnt(0)" ::: "memory");
        __builtin_amdgcn_sched_barrier(0);
        __builtin_amdgcn_s_barrier();          // all waves' chunks visible
        __builtin_amdgcn_sched_barrier(0);
        asm volatile("" ::: "memory");

        const s8v* Avp = (const s8v*)As[cur];
        const s8v* Bvp = (const s8v*)Bs[cur];
        #pragma unroll
        for (int t = 0; t < 2; ++t) {          // two k-steps of 32 within BK=64
            s8v af[4], bf[4];
            #pragma unroll
            for (int i = 0; i < 4; ++i) {
                af[i] = Avp[((wr * 4 + i) * 2 + t) * 64 + lane];
                bf[i] = Bvp[((wc * 4 + i) * 2 + t) * 64 + lane];
            }
            #pragma unroll
            for (int i = 0; i < 4; ++i)
                #pragma unroll
                for (int j = 0; j < 4; ++j)
                    acc[i][j] = __builtin_amdgcn_mfma_f32_16x16x32_bf16(
                        af[i], bf[j], acc[i][j], 0, 0, 0);
        }

        asm volatile("" ::: "memory");
        __builtin_amdgcn_sched_barrier(0);
        __builtin_amdgcn_s_barrier();          // all waves done reading buf[cur]
        __builtin_amdgcn_sched_barrier(0);

        if (kt < NT - 2) {                     // DMA tile kt+2 into buf[cur]
            #pragma unroll
            for (int u = 0; u < 4; ++u)
                gload_lds16(aptr[u] + (kt + 2) * BK, &As[cur][aoff[u]]);
            #pragma unroll
            for (int u = 0; u < 2; ++u)
                gload_lds16(bptr[u] + (kt + 2) * BK, &Bs[cur][boff[u]]);
        }
    }

    // Epilogue: C/D layout col = lane&15, row = (lane>>4)*4 + reg  [m89]
    const int col_base = bn * BN + wc * 64;
    const int row_base = bm * BM + wr * 64 + lq * 4;
    #pragma unroll
    for (int j = 0; j < 4; ++j) {
        const int col = col_base + j * 16 + l15;
        const float bv = bias[col];
        #pragma unroll
        for (int i = 0; i < 4; ++i) {
            const int row = row_base + i * 16;
            #pragma unroll
            for (int r = 0; r < 4; ++r)
                out[(size_t)(row + r) * N_TOT + col] = acc[i][j][r] + bv;
        }
    }
}

extern "C" void kernel_launch(void* const* d_in, const int* in_sizes, int n_in,
                              void* d_out, int out_size, void* d_ws, size_t ws_size,
                              hipStream_t stream) {
    const float* x     = (const float*)d_in[0];   // [2,4096,1024]
    const float* W     = (const float*)d_in[1];   // [3072,1024]
    const float* b     = (const float*)d_in[2];   // [3072]
    const float* Aq    = (const float*)d_in[3];
    const float* Bq    = (const float*)d_in[4];
    const float* Ak    = (const float*)d_in[5];
    const float* Bk    = (const float*)d_in[6];
    const float* Av    = (const float*)d_in[7];
    const float* Bv    = (const float*)d_in[8];
    const float* alpha = (const float*)d_in[9];
    float* out = (float*)d_out;

    unsigned short* xb = (unsigned short*)d_ws;                                      // 16 MB
    unsigned short* Wb = (unsigned short*)((char*)d_ws + (size_t)M_TOT * K_TOT * 2); // +6 MB

    prep<<<8192 + N_TOT, 256, 0, stream>>>((const float4*)x, (ushort4*)xb,
                                           W, Aq, Bq, Ak, Bk, Av, Bv, alpha, Wb);

    // 32 M-tiles x 24 N-tiles = 768 blocks = exactly 3 rounds of 256 CUs
    gemm_bt<<<(M_TOT / BM) * (N_TOT / BN), 512, 0, stream>>>(xb, Wb, b, out);
}

// Round 3
// 253.962 us; speedup vs baseline: 1.0674x; 1.0277x over previous
//
#include <hip/hip_runtime.h>
#include <stdint.h>

// Problem constants
#define DIM    1024
#define RANK   16
#define M_TOT  8192          // 2*4096 rows of x
#define N_TOT  3072          // 3*DIM output features
#define K_TOT  1024

// GEMM tiling: block = 256x128, BK=64, 8 waves (4M x 2N), wave tile 64x64
#define BM 256
#define BN 128
#define BK 64
#define NT (K_TOT / BK)      // 16 K-tiles

typedef __attribute__((ext_vector_type(8))) short  s8v;   // 8 x bf16 (raw bits)
typedef __attribute__((ext_vector_type(4))) float  f4v;   // MFMA acc

__device__ __forceinline__ unsigned short f2bf(float f) {
    union { float f; unsigned int u; } v; v.f = f;
    unsigned int u = v.u;
    u += 0x7FFFu + ((u >> 16) & 1u);   // round-to-nearest-even
    return (unsigned short)(u >> 16);
}

// Async global->LDS DMA, 16 B/lane. LDS dest is wave-uniform base + lane*16;
// global src carries the fragment swizzle (m173 pattern).
__device__ __forceinline__ void gload_lds16(const unsigned short* g,
                                            unsigned short* l) {
    __builtin_amdgcn_global_load_lds(
        (const __attribute__((address_space(1))) void*)g,
        (__attribute__((address_space(3))) void*)l,
        16, 0, 0);
}

// ---------------- Kernel 1: fused prep (rewritten) ----------------
// blocks [0, 2048):    x fp32 -> bf16, 4 float4 per thread (grid-stride x4)
// blocks [2048, 2240): fold LoRA into W. One block per 16 output rows:
//   A[16xDIM] staged once into 64 VGPRs (float4/thread) and reused for all
//   16 rows; alpha*B[16x16] in LDS; W read/store fully vectorized.
__global__ __launch_bounds__(256)
void prep(const float4* __restrict__ x, ushort4* __restrict__ xb,
          const float* __restrict__ W,
          const float* __restrict__ Aq, const float* __restrict__ Bq,
          const float* __restrict__ Ak, const float* __restrict__ Bk,
          const float* __restrict__ Av, const float* __restrict__ Bv,
          const float* __restrict__ alpha_p,
          unsigned short* __restrict__ Wb) {
    const int tid = threadIdx.x;
    if (blockIdx.x < 2048) {
        int i = blockIdx.x * 256 + tid;          // 2048*256*4 = 2097152 exact
        #pragma unroll
        for (int k = 0; k < 4; ++k) {
            float4 v = x[i];
            ushort4 o;
            o.x = f2bf(v.x); o.y = f2bf(v.y); o.z = f2bf(v.z); o.w = f2bf(v.w);
            xb[i] = o;
            i += 2048 * 256;
        }
    } else {
        const int bid2 = blockIdx.x - 2048;      // 0..191
        const int sel  = bid2 >> 6;              // 0=q 1=k 2=v
        const int rb   = bid2 & 63;              // row block: rows rb*16..+16
        const float* Am = (sel == 0) ? Aq : (sel == 1) ? Ak : Av;  // [RANK, DIM]
        const float* Bm = (sel == 0) ? Bq : (sel == 1) ? Bk : Bv;  // [DIM, RANK]

        __shared__ float sb[16][RANK];
        {   // alpha*B[16 rows][16 ranks]: thread t -> (row t>>4, r t&15), coalesced
            const int row = rb * 16 + (tid >> 4);
            sb[tid >> 4][tid & 15] = alpha_p[0] * Bm[row * RANK + (tid & 15)];
        }
        __syncthreads();

        float4 a4[RANK];                          // A column-slice, 64 VGPRs
        #pragma unroll
        for (int r = 0; r < RANK; ++r)
            a4[r] = ((const float4*)(Am + r * DIM))[tid];   // tid = d/4, coalesced

        #pragma unroll
        for (int row = 0; row < 16; ++row) {
            const int o = sel * 1024 + rb * 16 + row;       // output row 0..3071
            float4 w = ((const float4*)(W + (size_t)o * DIM))[tid];
            #pragma unroll
            for (int r = 0; r < RANK; ++r) {
                const float s = sb[row][r];       // LDS broadcast (uniform addr)
                w.x += s * a4[r].x; w.y += s * a4[r].y;
                w.z += s * a4[r].z; w.w += s * a4[r].w;
            }
            ushort4 ov;
            ov.x = f2bf(w.x); ov.y = f2bf(w.y); ov.z = f2bf(w.z); ov.w = f2bf(w.w);
            ((ushort4*)(Wb + (size_t)o * DIM))[tid] = ov;
        }
    }
}

// ---------------- Kernel 2: bf16 MFMA GEMM, C = Xb * Wb^T + bias ----------------
// Depth-2 counted-vmcnt DMA pipeline (kept from round 2), with the block->tile
// mapping inverted for L2 residency: each XCD owns a 4-bm x 24-bn chunk,
// bn-fastest, so its ~32 concurrent blocks share ~2 A-slabs (1 MB, L2-hits,
// 24x reuse) while B streams from an L3-resident 6 MB Wb. Round 2's mapping
// (bm-fast) streamed all 16 MB of Xb through each 4 MB L2 -> FETCH 200 MB,
// staging-BW-bound at ~6100 cyc/iter.
__global__ __launch_bounds__(512, 2)
void gemm_bt(const unsigned short* __restrict__ Xb,
             const unsigned short* __restrict__ Wb,
             const float* __restrict__ bias,
             float* __restrict__ out) {
    __shared__ __align__(16) unsigned short As[2][BM * BK];  // 2 x 32 KB
    __shared__ __align__(16) unsigned short Bs[2][BN * BK];  // 2 x 16 KB

    const int tid  = threadIdx.x;
    const int wave = tid >> 6;       // 0..7
    const int lane = tid & 63;
    const int l15  = lane & 15;
    const int lq   = lane >> 4;      // 0..3
    const int wr   = wave >> 1;      // M quadrant 0..3 (64 rows each)
    const int wc   = wave & 1;       // N half     0..1 (64 cols each)

    // XCD chunk = 4 bm x 24 bn, bn-fastest. blockIdx round-robins XCDs (m09),
    // bijective: xcd in [0,8), s in [0,96) -> bm = xcd*4 + s/24, bn = s%24.
    const int bid = blockIdx.x;
    const int xcd = bid & 7;
    const int s   = bid >> 3;        // 0..95
    const int bn  = s % 24;
    const int bm  = xcd * 4 + s / 24;   // 0..31

    // Staging assignment: wave w owns A chunks [w*4, +4), B chunks [w*2, +2).
    // Chunk c of a tile: rows (c>>1)*16 + l15, k-cols (c&1)*32 + lq*8.
    // LDS chunk c = 1KB at offset c*512 halves, lane l owns [c*512+l*8, +8)
    // = exactly the linear wave-uniform-base + lane*16B order the DMA writes.
    const unsigned short* aptr[4];
    const unsigned short* bptr[2];
    int aoff[4], boff[2];
    #pragma unroll
    for (int u = 0; u < 4; ++u) {
        const int c   = wave * 4 + u;                // 0..31
        const int row = ((c >> 1) << 4) + l15;       // 0..255
        const int col = ((c & 1) << 5) + (lq << 3);  // 0..56
        aptr[u] = Xb + (size_t)(bm * BM + row) * K_TOT + col;
        aoff[u] = c * 512;
    }
    #pragma unroll
    for (int u = 0; u < 2; ++u) {
        const int c   = wave * 2 + u;                // 0..15
        const int row = ((c >> 1) << 4) + l15;       // 0..127
        const int col = ((c & 1) << 5) + (lq << 3);
        bptr[u] = Wb + (size_t)(bn * BN + row) * K_TOT + col;
        boff[u] = c * 512;
    }

    // Prologue: tiles 0 and 1 in flight (12 loads/wave)
    #pragma unroll
    for (int t = 0; t < 2; ++t) {
        #pragma unroll
        for (int u = 0; u < 4; ++u) gload_lds16(aptr[u] + t * BK, &As[t][aoff[u]]);
        #pragma unroll
        for (int u = 0; u < 2; ++u) gload_lds16(bptr[u] + t * BK, &Bs[t][boff[u]]);
    }

    f4v acc[4][4] = {};

    #define COMPUTE(curbuf)                                                      \
    {                                                                            \
        const s8v* Avp = (const s8v*)As[curbuf];                                 \
        const s8v* Bvp = (const s8v*)Bs[curbuf];                                 \
        _Pragma("unroll")                                                        \
        for (int t = 0; t < 2; ++t) {                                            \
            s8v af[4], bf[4];                                                    \
            _Pragma("unroll")                                                    \
            for (int i = 0; i < 4; ++i) {                                        \
                af[i] = Avp[((wr * 4 + i) * 2 + t) * 64 + lane];                 \
                bf[i] = Bvp[((wc * 4 + i) * 2 + t) * 64 + lane];                 \
            }                                                                    \
            _Pragma("unroll")                                                    \
            for (int i = 0; i < 4; ++i)                                          \
                _Pragma("unroll")                                                \
                for (int j = 0; j < 4; ++j)                                      \
                    acc[i][j] = __builtin_amdgcn_mfma_f32_16x16x32_bf16(         \
                        af[i], bf[j], acc[i][j], 0, 0, 0);                       \
        }                                                                        \
    }

    // Main loop: kt = 0..NT-3. Steady state: entering iter kt there are 12
    // loads in flight (tiles kt, kt+1); vmcnt(6) = tile kt landed, kt+1 stays
    // in flight across both barriers (T4: never drain to 0 mid-loop).
    #pragma unroll 2
    for (int kt = 0; kt < NT - 2; ++kt) {
        const int cur = kt & 1;
        asm volatile("s_waitcnt vmcnt(6)" ::: "memory");
        __builtin_amdgcn_sched_barrier(0);
        __builtin_amdgcn_s_barrier();          // all waves' tile-kt chunks visible
        __builtin_amdgcn_sched_barrier(0);

        COMPUTE(cur);

        __builtin_amdgcn_sched_barrier(0);
        __builtin_amdgcn_s_barrier();          // all waves done reading buf[cur]
        __builtin_amdgcn_sched_barrier(0);

        #pragma unroll
        for (int u = 0; u < 4; ++u)
            gload_lds16(aptr[u] + (kt + 2) * BK, &As[cur][aoff[u]]);
        #pragma unroll
        for (int u = 0; u < 2; ++u)
            gload_lds16(bptr[u] + (kt + 2) * BK, &Bs[cur][boff[u]]);
    }

    // Peeled iter NT-2: tile NT-1 (6 loads) still in flight; no new DMA, and
    // no trailing barrier needed (no writes target buf[0] afterwards).
    asm volatile("s_waitcnt vmcnt(6)" ::: "memory");
    __builtin_amdgcn_sched_barrier(0);
    __builtin_amdgcn_s_barrier();
    __builtin_amdgcn_sched_barrier(0);
    COMPUTE(0);

    // Peeled iter NT-1: drain everything.
    asm volatile("s_waitcnt vmcnt(0)" ::: "memory");
    __builtin_amdgcn_sched_barrier(0);
    __builtin_amdgcn_s_barrier();
    __builtin_amdgcn_sched_barrier(0);
    COMPUTE(1);
    #undef COMPUTE

    // Epilogue: C/D layout col = lane&15, row = (lane>>4)*4 + reg  [m89]
    const int col_base = bn * BN + wc * 64;
    const int row_base = bm * BM + wr * 64 + lq * 4;
    #pragma unroll
    for (int j = 0; j < 4; ++j) {
        const int col = col_base + j * 16 + l15;
        const float bv = bias[col];
        #pragma unroll
        for (int i = 0; i < 4; ++i) {
            const int row = row_base + i * 16;
            #pragma unroll
            for (int r = 0; r < 4; ++r)
                out[(size_t)(row + r) * N_TOT + col] = acc[i][j][r] + bv;
        }
    }
}

extern "C" void kernel_launch(void* const* d_in, const int* in_sizes, int n_in,
                              void* d_out, int out_size, void* d_ws, size_t ws_size,
                              hipStream_t stream) {
    const float* x     = (const float*)d_in[0];   // [2,4096,1024]
    const float* W     = (const float*)d_in[1];   // [3072,1024]
    const float* b     = (const float*)d_in[2];   // [3072]
    const float* Aq    = (const float*)d_in[3];
    const float* Bq    = (const float*)d_in[4];
    const float* Ak    = (const float*)d_in[5];
    const float* Bk    = (const float*)d_in[6];
    const float* Av    = (const float*)d_in[7];
    const float* Bv    = (const float*)d_in[8];
    const float* alpha = (const float*)d_in[9];
    float* out = (float*)d_out;

    unsigned short* xb = (unsigned short*)d_ws;                                      // 16 MB
    unsigned short* Wb = (unsigned short*)((char*)d_ws + (size_t)M_TOT * K_TOT * 2); // +6 MB

    prep<<<2048 + 192, 256, 0, stream>>>((const float4*)x, (ushort4*)xb,
                                         W, Aq, Bq, Ak, Bk, Av, Bv, alpha, Wb);

    // 32 M-tiles x 24 N-tiles = 768 blocks = exactly 3 rounds of 256 CUs
    gemm_bt<<<(M_TOT / BM) * (N_TOT / BN), 512, 0, stream>>>(xb, Wb, b, out);
}

// Round 4
// 233.412 us; speedup vs baseline: 1.1614x; 1.0880x over previous
//
#include <hip/hip_runtime.h>
#include <stdint.h>

// Problem constants
#define DIM    1024
#define RANK   16
#define M_TOT  8192          // 2*4096 rows of x
#define N_TOT  3072          // 3*DIM output features
#define K_TOT  1024

// GEMM tiling: block = 256x128, BK=64, 8 waves (4M x 2N), wave tile 64x64
#define BM 256
#define BN 128
#define BK 64
#define NT (K_TOT / BK)      // 16 K-tiles

typedef __attribute__((ext_vector_type(8))) short  s8v;   // 8 x bf16 (raw bits)
typedef __attribute__((ext_vector_type(4))) float  f4v;   // MFMA acc

__device__ __forceinline__ unsigned short f2bf(float f) {
    union { float f; unsigned int u; } v; v.f = f;
    unsigned int u = v.u;
    u += 0x7FFFu + ((u >> 16) & 1u);   // round-to-nearest-even
    return (unsigned short)(u >> 16);
}

// Async global->LDS DMA, 16 B/lane. LDS dest is wave-uniform base + lane*16;
// global src carries the fragment swizzle (m173 pattern).
__device__ __forceinline__ void gload_lds16(const unsigned short* g,
                                            unsigned short* l) {
    __builtin_amdgcn_global_load_lds(
        (const __attribute__((address_space(1))) void*)g,
        (__attribute__((address_space(3))) void*)l,
        16, 0, 0);
}

// ---------------- Kernel 1: fused prep (unchanged from round 3) ----------------
__global__ __launch_bounds__(256)
void prep(const float4* __restrict__ x, ushort4* __restrict__ xb,
          const float* __restrict__ W,
          const float* __restrict__ Aq, const float* __restrict__ Bq,
          const float* __restrict__ Ak, const float* __restrict__ Bk,
          const float* __restrict__ Av, const float* __restrict__ Bv,
          const float* __restrict__ alpha_p,
          unsigned short* __restrict__ Wb) {
    const int tid = threadIdx.x;
    if (blockIdx.x < 2048) {
        int i = blockIdx.x * 256 + tid;          // 2048*256*4 = 2097152 exact
        #pragma unroll
        for (int k = 0; k < 4; ++k) {
            float4 v = x[i];
            ushort4 o;
            o.x = f2bf(v.x); o.y = f2bf(v.y); o.z = f2bf(v.z); o.w = f2bf(v.w);
            xb[i] = o;
            i += 2048 * 256;
        }
    } else {
        const int bid2 = blockIdx.x - 2048;      // 0..191
        const int sel  = bid2 >> 6;              // 0=q 1=k 2=v
        const int rb   = bid2 & 63;              // rows rb*16..+16
        const float* Am = (sel == 0) ? Aq : (sel == 1) ? Ak : Av;  // [RANK, DIM]
        const float* Bm = (sel == 0) ? Bq : (sel == 1) ? Bk : Bv;  // [DIM, RANK]

        __shared__ float sb[16][RANK];
        {
            const int row = rb * 16 + (tid >> 4);
            sb[tid >> 4][tid & 15] = alpha_p[0] * Bm[row * RANK + (tid & 15)];
        }
        __syncthreads();

        float4 a4[RANK];                          // A column-slice, 64 VGPRs
        #pragma unroll
        for (int r = 0; r < RANK; ++r)
            a4[r] = ((const float4*)(Am + r * DIM))[tid];

        #pragma unroll
        for (int row = 0; row < 16; ++row) {
            const int o = sel * 1024 + rb * 16 + row;
            float4 w = ((const float4*)(W + (size_t)o * DIM))[tid];
            #pragma unroll
            for (int r = 0; r < RANK; ++r) {
                const float s = sb[row][r];
                w.x += s * a4[r].x; w.y += s * a4[r].y;
                w.z += s * a4[r].z; w.w += s * a4[r].w;
            }
            ushort4 ov;
            ov.x = f2bf(w.x); ov.y = f2bf(w.y); ov.z = f2bf(w.z); ov.w = f2bf(w.w);
            ((ushort4*)(Wb + (size_t)o * DIM))[tid] = ov;
        }
    }
}

// ---------------- Kernel 2: bf16 MFMA GEMM, C = Xb * Wb^T + bias ----------------
// Phase-interleaved ring-3 pipeline (T3+T4+T5 on verified round-3 addressing):
//   LDS ring of 3 K-tile slots (48 KB each, 144 KB total, 1 block/CU).
//   Quad q (one K-tile, 2 phases of 16 MFMA): reads slot q%3; DMA issues for
//   tile q+2 go to slot (q+2)%3 == (q-1)%3, freed at quad q-1's end. Each
//   phase: {8 ds_read_b128 || 3 global_load_lds} -> barrier -> lgkmcnt(0) ->
//   setprio(1) -> 16 MFMA -> setprio(0) -> barrier. One vmcnt(6) per quad
//   (before its closing barrier): tile q+1's 6 loads complete, tile q+2's 6
//   stay in flight -- counted, never 0 until the 2-quad tail. Loads issue
//   continuously (3/phase) instead of per-iteration bursts (rounds 0-3 all
//   pinned at ~1 B/cyc/wave staging delivery on burst issue).
__global__ __launch_bounds__(512, 2)
void gemm_bt(const unsigned short* __restrict__ Xb,
             const unsigned short* __restrict__ Wb,
             const float* __restrict__ bias,
             float* __restrict__ out) {
    __shared__ __align__(16) unsigned short As[3][BM * BK];  // 3 x 32 KB
    __shared__ __align__(16) unsigned short Bs[3][BN * BK];  // 3 x 16 KB

    const int tid  = threadIdx.x;
    const int wave = tid >> 6;       // 0..7
    const int lane = tid & 63;
    const int l15  = lane & 15;
    const int lq   = lane >> 4;      // 0..3
    const int wr   = wave >> 1;      // M quadrant 0..3 (64 rows each)
    const int wc   = wave & 1;       // N half     0..1 (64 cols each)

    // XCD chunk = 4 bm x 24 bn, bn-fastest (round-3 mapping: FETCH 200->86 MB).
    const int bid = blockIdx.x;
    const int xcd = bid & 7;
    const int s   = bid >> 3;        // 0..95
    const int bn  = s % 24;
    const int bm  = xcd * 4 + s / 24;   // 0..31

    // Staging: A = 32 chunks of 1 KB, wave w owns chunks w*4..+3.
    //          B = 16 chunks, wave w owns chunks w*2..+1.
    // Chunk c: rows (c>>1)*16 + l15, k-cols (c&1)*32 + lq*8 (8 halves/lane).
    // LDS chunk c = wave-uniform base c*1024B + lane*16B (linear DMA order).
    const unsigned short* aptr[4];
    const unsigned short* bptr[2];
    int aoff[4], boff[2];
    #pragma unroll
    for (int u = 0; u < 4; ++u) {
        const int c   = wave * 4 + u;                // 0..31
        const int row = ((c >> 1) << 4) + l15;       // 0..255
        const int col = ((c & 1) << 5) + (lq << 3);  // 0..56
        aptr[u] = Xb + (size_t)(bm * BM + row) * K_TOT + col;
        aoff[u] = c * 512;
    }
    #pragma unroll
    for (int u = 0; u < 2; ++u) {
        const int c   = wave * 2 + u;                // 0..15
        const int row = ((c >> 1) << 4) + l15;       // 0..127
        const int col = ((c & 1) << 5) + (lq << 3);
        bptr[u] = Wb + (size_t)(bn * BN + row) * K_TOT + col;
        boff[u] = c * 512;
    }

    // Prologue: tiles 0,1 -> slots 0,1 (12 loads/wave); tile 0 resident,
    // tile 1's 6 stay in flight.
    #pragma unroll
    for (int t = 0; t < 2; ++t) {
        #pragma unroll
        for (int u = 0; u < 4; ++u) gload_lds16(aptr[u] + t * BK, &As[t][aoff[u]]);
        #pragma unroll
        for (int u = 0; u < 2; ++u) gload_lds16(bptr[u] + t * BK, &Bs[t][boff[u]]);
    }
    asm volatile("s_waitcnt vmcnt(6)" ::: "memory");
    __builtin_amdgcn_sched_barrier(0);
    __builtin_amdgcn_s_barrier();
    __builtin_amdgcn_sched_barrier(0);

    f4v acc[4][4] = {};

    #pragma unroll 1
    for (int q = 0; q < NT; ++q) {
        const int r    = q % 3;               // compute slot (tile q)
        const int r2   = (q + 2) % 3;         // DMA target slot (tile q+2)
        const int kg   = (q + 2) * BK;
        const bool iss = (q + 2) < NT;
        const s8v* Avp = (const s8v*)As[r];
        const s8v* Bvp = (const s8v*)Bs[r];

        // ---------------- phase A (t = 0) ----------------
        {
            s8v af[4], bf[4];
            #pragma unroll
            for (int i = 0; i < 4; ++i) {
                af[i] = Avp[((wr * 4 + i) * 2 + 0) * 64 + lane];
                bf[i] = Bvp[((wc * 4 + i) * 2 + 0) * 64 + lane];
            }
            if (iss) {   // 3 of tile q+2's 6 loads
                gload_lds16(aptr[0] + kg, &As[r2][aoff[0]]);
                gload_lds16(aptr[1] + kg, &As[r2][aoff[1]]);
                gload_lds16(bptr[0] + kg, &Bs[r2][boff[0]]);
            }
            __builtin_amdgcn_sched_barrier(0);
            __builtin_amdgcn_s_barrier();
            asm volatile("s_waitcnt lgkmcnt(0)" ::: "memory");
            __builtin_amdgcn_sched_barrier(0);
            __builtin_amdgcn_s_setprio(1);
            #pragma unroll
            for (int i = 0; i < 4; ++i)
                #pragma unroll
                for (int j = 0; j < 4; ++j)
                    acc[i][j] = __builtin_amdgcn_mfma_f32_16x16x32_bf16(
                        af[i], bf[j], acc[i][j], 0, 0, 0);
            __builtin_amdgcn_s_setprio(0);
            __builtin_amdgcn_sched_barrier(0);
            __builtin_amdgcn_s_barrier();
            __builtin_amdgcn_sched_barrier(0);
        }

        // ---------------- phase B (t = 1) ----------------
        {
            s8v af[4], bf[4];
            #pragma unroll
            for (int i = 0; i < 4; ++i) {
                af[i] = Avp[((wr * 4 + i) * 2 + 1) * 64 + lane];
                bf[i] = Bvp[((wc * 4 + i) * 2 + 1) * 64 + lane];
            }
            if (iss) {   // remaining 3 loads of tile q+2
                gload_lds16(aptr[2] + kg, &As[r2][aoff[2]]);
                gload_lds16(aptr[3] + kg, &As[r2][aoff[3]]);
                gload_lds16(bptr[1] + kg, &Bs[r2][boff[1]]);
            }
            __builtin_amdgcn_sched_barrier(0);
            __builtin_amdgcn_s_barrier();
            asm volatile("s_waitcnt lgkmcnt(0)" ::: "memory");
            __builtin_amdgcn_sched_barrier(0);
            __builtin_amdgcn_s_setprio(1);
            #pragma unroll
            for (int i = 0; i < 4; ++i)
                #pragma unroll
                for (int j = 0; j < 4; ++j)
                    acc[i][j] = __builtin_amdgcn_mfma_f32_16x16x32_bf16(
                        af[i], bf[j], acc[i][j], 0, 0, 0);
            __builtin_amdgcn_s_setprio(0);
            __builtin_amdgcn_sched_barrier(0);
            // End-of-quad wait: tile q+1 resident for next quad's reads;
            // tile q+2's 6 loads stay in flight (counted, not drained).
            if (q < NT - 2) {
                asm volatile("s_waitcnt vmcnt(6)" ::: "memory");
            } else if (q == NT - 2) {
                asm volatile("s_waitcnt vmcnt(0)" ::: "memory");
            }
            __builtin_amdgcn_sched_barrier(0);
            __builtin_amdgcn_s_barrier();
            __builtin_amdgcn_sched_barrier(0);
        }
    }

    // Epilogue: C/D layout col = lane&15, row = (lane>>4)*4 + reg  [m89]
    const int col_base = bn * BN + wc * 64;
    const int row_base = bm * BM + wr * 64 + lq * 4;
    #pragma unroll
    for (int j = 0; j < 4; ++j) {
        const int col = col_base + j * 16 + l15;
        const float bv = bias[col];
        #pragma unroll
        for (int i = 0; i < 4; ++i) {
            const int row = row_base + i * 16;
            #pragma unroll
            for (int r = 0; r < 4; ++r)
                out[(size_t)(row + r) * N_TOT + col] = acc[i][j][r] + bv;
        }
    }
}

extern "C" void kernel_launch(void* const* d_in, const int* in_sizes, int n_in,
                              void* d_out, int out_size, void* d_ws, size_t ws_size,
                              hipStream_t stream) {
    const float* x     = (const float*)d_in[0];   // [2,4096,1024]
    const float* W     = (const float*)d_in[1];   // [3072,1024]
    const float* b     = (const float*)d_in[2];   // [3072]
    const float* Aq    = (const float*)d_in[3];
    const float* Bq    = (const float*)d_in[4];
    const float* Ak    = (const float*)d_in[5];
    const float* Bk    = (const float*)d_in[6];
    const float* Av    = (const float*)d_in[7];
    const float* Bv    = (const float*)d_in[8];
    const float* alpha = (const float*)d_in[9];
    float* out = (float*)d_out;

    unsigned short* xb = (unsigned short*)d_ws;                                      // 16 MB
    unsigned short* Wb = (unsigned short*)((char*)d_ws + (size_t)M_TOT * K_TOT * 2); // +6 MB

    prep<<<2048 + 192, 256, 0, stream>>>((const float4*)x, (ushort4*)xb,
                                         W, Aq, Bq, Ak, Bk, Av, Bv, alpha, Wb);

    // 32 M-tiles x 24 N-tiles = 768 blocks = exactly 3 rounds of 256 CUs
    gemm_bt<<<(M_TOT / BM) * (N_TOT / BN), 512, 0, stream>>>(xb, Wb, b, out);
}